// Round 14
// baseline (840.724 us; speedup 1.0000x reference)
//
#include <hip/hip_runtime.h>
#include <math.h>

#define NN 100000      // nodes
#define NE 3200000     // edges
#define NIN 128
#define HH 64
#define NB 2048        // graphs
#define RO 1024

#define NT    1563     // (NN+63)/64
#define NBK   391      // ceil(NN/256) dst-buckets of 256 nodes
#define BINB  782      // ceil(NE/4096)
#define GCB   391      // ceil(NN/256) gcnt blocks
#define PCAP  10240    // k_place LDS staging capacity (edges)
#define PREPN 112640   // 8192 small + 55296 lstm + 49152 final frag ids
#define PREPB 440      // ceil(PREPN/256)
#define SRCMASK 0x1FFFF

typedef unsigned short u16;
typedef __attribute__((ext_vector_type(8))) short short8;
typedef __attribute__((ext_vector_type(4))) float f32x4;

__device__ __forceinline__ float sigmoidf_(float x){ return 1.f/(1.f+expf(-x)); }
__device__ __forceinline__ u16 f2bf(float f){
  unsigned u = __float_as_uint(f);
  return (u16)((u + 0x7FFFu + ((u>>16)&1u)) >> 16);
}
__device__ __forceinline__ float bf2f(u16 v){
  return __uint_as_float(((unsigned)v) << 16);
}

// ---------------- fused: bucket hist (LDS) + graph counting + weight prep ----------------
__global__ void k_bkcnt_prep(const int* __restrict__ dst, const int* __restrict__ batch,
                             int* __restrict__ bkcnt, int* __restrict__ gcnt,
                             const float* __restrict__ Wp, const float* __restrict__ Wl,
                             const float* __restrict__ Wr,
                             const float* __restrict__ sWih, const float* __restrict__ sWhh,
                             const float* __restrict__ rWih, const float* __restrict__ rWhh,
                             const float* __restrict__ lWih, const float* __restrict__ lWhh,
                             const float* __restrict__ Wsp,
                             u16* __restrict__ pB_proj, u16* __restrict__ pB_sage,
                             u16* __restrict__ pB_gruS, u16* __restrict__ pB_gruR,
                             u16* __restrict__ pB_lstm, u16* __restrict__ pB_fin){
  __shared__ int hist[NBK];
  const int t = threadIdx.x;
  if (blockIdx.x < BINB){
    for (int i = t; i < NBK; i += 256) hist[i] = 0;
    __syncthreads();
    const int e0 = blockIdx.x * 4096;
    const int cntE = min(4096, NE - e0);
    for (int idx = t; idx < cntE; idx += 256)
      atomicAdd(&hist[dst[e0 + idx] >> 8], 1);
    __syncthreads();
    for (int i = t; i < NBK; i += 256)
      if (hist[i]) atomicAdd(&bkcnt[i], hist[i]);
    return;
  }
  int r = blockIdx.x - BINB;
  if (r < GCB){
    int n = r*256 + t;
    if (n < NN) atomicAdd(&gcnt[batch[n]], 1);
    return;
  }
  int id = (r - GCB)*256 + t;
  if (id >= PREPN) return;
  const float* sp; u16* d;
  if (id < 1024){
    int fi = id; d = pB_proj + (size_t)fi*8;
    int lane = fi&63, kt=(fi>>6)&3, ct=fi>>8;
    int rr = ct*16 + (lane&15), k0 = kt*32 + (lane>>4)*8;
    sp = &Wp[(size_t)rr*NIN + k0];
  } else if (id < 2048){
    int fi = id - 1024; d = pB_sage + (size_t)fi*8;
    int lane = fi&63, kt=(fi>>6)&3, ct=fi>>8;
    int rr = ct*16 + (lane&15), k0 = kt*32 + (lane>>4)*8;
    sp = (k0 < 64) ? &Wl[(size_t)rr*HH + k0] : &Wr[(size_t)rr*HH + (k0-64)];
  } else if (id < 8192){
    int base = id - 2048;
    const float* Wih; const float* Whh; u16* pb; int fi;
    if (base < 3072){ pb = pB_gruS; Wih = sWih; Whh = sWhh; fi = base; }
    else            { pb = pB_gruR; Wih = rWih; Whh = rWhh; fi = base - 3072; }
    int lane = fi&63, kt=(fi>>6)&1, c2=fi>>7;
    const float* W2 = (c2 < 12) ? Wih : Whh;
    int ct = (c2 < 12) ? c2 : c2 - 12;
    int rr = ct*16 + (lane&15), k0 = kt*32 + (lane>>4)*8;
    sp = &W2[(size_t)rr*HH + k0];
    d = pb + (size_t)fi*8;
  } else if (id < 63488){
    // LSTM W = [Wih | Whh] as 768 x 576; frags (ctg 0..47, ktg 0..17, lane)
    int fi = id - 8192;
    int ctg = fi / 1152;
    int rem = fi - ctg*1152;
    int ktg = rem >> 6, lane = rem & 63;
    int rr = ctg*16 + (lane&15), k0 = ktg*32 + (lane>>4)*8;
    sp = (k0 < 384) ? &lWih[(size_t)rr*384 + k0] : &lWhh[(size_t)rr*192 + (k0-384)];
    d = pB_lstm + (size_t)fi*8;
  } else {
    // final W_sp 1024 x 384; frags (ctg 0..63, ktg 0..11, lane)
    int fi = id - 63488;
    int ctg = fi / 768;
    int rem = fi - ctg*768;
    int ktg = rem >> 6, lane = rem & 63;
    int rr = ctg*16 + (lane&15), k0 = ktg*32 + (lane>>4)*8;
    sp = &Wsp[(size_t)rr*384 + k0];
    d = pB_fin + (size_t)fi*8;
  }
  #pragma unroll
  for (int q = 0; q < 8; ++q) d[q] = f2bf(sp[q]);
}

// ---------------- small scans: block0 buckets(391), block1 graphs(2048) ----------------
__global__ __launch_bounds__(256) void k_scan_small(
    const int* __restrict__ bkcnt, int* __restrict__ bkbase, int* __restrict__ bcur,
    const int* __restrict__ gcnt, int* __restrict__ growptr){
  __shared__ int sb[256];
  const int t = threadIdx.x;
  if (blockIdx.x == 0){
    int loc[2]; int s = 0;
    #pragma unroll
    for (int q = 0; q < 2; ++q){ int i = t*2+q; loc[q] = (i < NBK) ? bkcnt[i] : 0; s += loc[q]; }
    sb[t] = s; __syncthreads();
    int v = s;
    for (int o = 1; o < 256; o <<= 1){
      int u = (t >= o) ? sb[t-o] : 0; __syncthreads();
      sb[t] += u; __syncthreads();
    }
    int run = sb[t] - v;
    #pragma unroll
    for (int q = 0; q < 2; ++q){
      int i = t*2+q;
      if (i < NBK){ bkbase[i] = run; bcur[i] = run; run += loc[q]; }
    }
    if (t == 255) bkbase[NBK] = run;    // = NE
  } else {
    int base = t*8;
    int loc[8]; int s = 0;
    #pragma unroll
    for (int q = 0; q < 8; ++q){ loc[q] = gcnt[base+q]; s += loc[q]; }
    sb[t] = s; __syncthreads();
    int v = s;
    for (int o = 1; o < 256; o <<= 1){
      int u = (t >= o) ? sb[t-o] : 0; __syncthreads();
      sb[t] += u; __syncthreads();
    }
    int run = sb[t] - v;
    #pragma unroll
    for (int q = 0; q < 8; ++q){ growptr[base+q] = run; run += loc[q]; }
    if (t == 255) growptr[NB] = run;
  }
}

// ---------------- pass 1: bin edges by dst>>8; packed payload src|(dlow<<17) ----------------
__global__ __launch_bounds__(256) void k_bin(
    const int* __restrict__ src, const int* __restrict__ dst,
    int* __restrict__ bcur, int* __restrict__ binned)
{
  __shared__ int hist[NBK];
  __shared__ int lbase[NBK];
  __shared__ int gbase[NBK];
  __shared__ int sb[512];
  __shared__ int stagep[4096];
  __shared__ u16 stageb[4096];
  const int t = threadIdx.x;
  const int e0 = blockIdx.x * 4096;
  const int cntE = min(4096, NE - e0);
  for (int i = t; i < NBK; i += 256) hist[i] = 0;
  __syncthreads();
  int2 ed[16];
  #pragma unroll
  for (int k = 0; k < 16; ++k){
    int idx = (k<<8) + t;
    if (idx < cntE){
      int e = e0 + idx;
      ed[k].x = src[e]; ed[k].y = dst[e];
      atomicAdd(&hist[ed[k].y >> 8], 1);
    } else ed[k].y = -1;
  }
  __syncthreads();
  sb[t]     = (t < NBK) ? hist[t] : 0;
  sb[t+256] = (t+256 < NBK) ? hist[t+256] : 0;
  __syncthreads();
  for (int off = 1; off < 512; off <<= 1){
    int v0 = (t >= off)     ? sb[t-off]     : 0;
    int v1 = (t+256 >= off) ? sb[t+256-off] : 0;
    __syncthreads();
    sb[t] += v0; sb[t+256] += v1;
    __syncthreads();
  }
  if (t < NBK)     lbase[t]     = sb[t]     - hist[t];
  if (t+256 < NBK) lbase[t+256] = sb[t+256] - hist[t+256];
  if (t < NBK)     gbase[t]     = (hist[t]     > 0) ? atomicAdd(&bcur[t],     hist[t])     : 0;
  if (t+256 < NBK) gbase[t+256] = (hist[t+256] > 0) ? atomicAdd(&bcur[t+256], hist[t+256]) : 0;
  __syncthreads();
  for (int i = t; i < NBK; i += 256) hist[i] = 0;
  __syncthreads();
  #pragma unroll
  for (int k = 0; k < 16; ++k){
    if (ed[k].y >= 0){
      int b = ed[k].y >> 8;
      int r = atomicAdd(&hist[b], 1);
      int p = lbase[b] + r;
      stagep[p] = ed[k].x | ((ed[k].y & 255) << 17);
      stageb[p] = (u16)b;
    }
  }
  __syncthreads();
  for (int i = t; i < cntE; i += 256){
    int b = stageb[i];
    binned[gbase[b] + (i - lbase[b])] = stagep[i];
  }
}

// ---------------- pass 2: per-bucket LDS counting sort; writes rowptr + col ----------------
__global__ __launch_bounds__(256) void k_place(
    const int* __restrict__ binned, const int* __restrict__ bkbase,
    int* __restrict__ rowptr, int* __restrict__ col)
{
  __shared__ int h[256];
  __shared__ int cur[256];
  __shared__ int sb2[256];
  __shared__ int stage[PCAP];
  const int t = threadIdx.x;
  const int b = blockIdx.x;
  const int n0 = b << 8;
  const int B0 = bkbase[b], B1 = bkbase[b+1];
  const int cntE = B1 - B0;
  h[t] = 0; __syncthreads();
  for (int i = t; i < cntE; i += 256){
    int e = binned[B0 + i];
    atomicAdd(&h[e >> 17], 1);
  }
  __syncthreads();
  sb2[t] = h[t]; __syncthreads();
  for (int off = 1; off < 256; off <<= 1){
    int v = (t >= off) ? sb2[t-off] : 0;
    __syncthreads();
    sb2[t] += v;
    __syncthreads();
  }
  int pre = sb2[t] - h[t];               // exclusive prefix within bucket
  if (n0 + t < NN) rowptr[n0 + t] = B0 + pre;
  if (b == NBK-1 && t == 0) rowptr[NN] = B1;   // = NE
  if (cntE <= PCAP){
    cur[t] = pre;
    __syncthreads();
    for (int i = t; i < cntE; i += 256){
      int e = binned[B0 + i];
      int idx = atomicAdd(&cur[e >> 17], 1);
      stage[idx] = e & SRCMASK;
    }
    __syncthreads();
    for (int i = t; i < cntE; i += 256) col[B0 + i] = stage[i];
  } else {
    cur[t] = B0 + pre;                    // global cursors (rare fallback)
    __syncthreads();
    for (int i = t; i < cntE; i += 256){
      int e = binned[B0 + i];
      int p = atomicAdd(&cur[e >> 17], 1);
      col[p] = e & SRCMASK;
    }
  }
}

// ---------------- proj = relu(x@W_p^T + b) via MFMA; init hs, hr, projb, hsb, hrb ----------------
__global__ __launch_bounds__(256) void k_proj(
    const float* __restrict__ x, const u16* __restrict__ pB, const float* __restrict__ bp,
    float* __restrict__ hs, float* __restrict__ hr,
    u16* __restrict__ projb, u16* __restrict__ hsb, u16* __restrict__ hrb)
{
  __shared__ u16 s_a[64][136];
  __shared__ u16 s_b[4*4*64*8];
  __shared__ float s_bias[64];
  const int t = threadIdx.x;
  const int n0 = blockIdx.x * 64;
  for (int idx = t; idx < 1024; idx += 256)
    ((short8*)s_b)[idx] = ((const short8*)pB)[idx];
  if (t < 64) s_bias[t] = bp[t];
  {
    int r = t>>2, cg = t&3, node = n0 + r;
    u16* d = &s_a[r][cg*32];
    if (node < NN){
      const float4* xp = (const float4*)&x[(size_t)node*NIN + cg*32];
      #pragma unroll
      for (int q = 0; q < 8; ++q){
        float4 v = xp[q];
        d[q*4+0]=f2bf(v.x); d[q*4+1]=f2bf(v.y); d[q*4+2]=f2bf(v.z); d[q*4+3]=f2bf(v.w);
      }
    } else {
      #pragma unroll
      for (int q = 0; q < 32; ++q) d[q] = 0;
    }
  }
  __syncthreads();
  const int lane = t & 63, nt = t >> 6;
  const int colp = lane & 15, rowg = lane >> 4;
  f32x4 acc[4];
  #pragma unroll
  for (int i = 0; i < 4; ++i) acc[i] = (f32x4){0.f,0.f,0.f,0.f};
  #pragma unroll
  for (int kt = 0; kt < 4; ++kt){
    short8 a = *(const short8*)&s_a[nt*16 + colp][kt*32 + rowg*8];
    #pragma unroll
    for (int ct = 0; ct < 4; ++ct){
      short8 b = *(const short8*)&s_b[((ct*4 + kt)*64 + lane)*8];
      acc[ct] = __builtin_amdgcn_mfma_f32_16x16x32_bf16(a, b, acc[ct], 0, 0, 0);
    }
  }
  #pragma unroll
  for (int reg = 0; reg < 4; ++reg){
    int node = n0 + nt*16 + rowg*4 + reg;
    if (node >= NN) continue;
    #pragma unroll
    for (int ct = 0; ct < 4; ++ct){
      int j = ct*16 + colp;
      float v = fmaxf(acc[ct][reg] + s_bias[j], 0.f);
      size_t o = (size_t)node*HH + j;
      hs[o] = v; hr[o] = v;
      u16 bv = f2bf(v);
      projb[o] = bv; hsb[o] = bv; hrb[o] = bv;
    }
  }
}

// ---------------- fused: mean-gather + SAGE MFMA; am bf16 -> aggb ----------------
// 64 nodes/block. Wave wv gathers nodes wv*16..wv*16+15 (8-slot/8-colgrp pattern),
// slot-0 lanes deposit agg bf16 into A-tile cols [0,64); hsb copied into cols [64,128).
__global__ __launch_bounds__(256) void k_aggsage(
    const u16* __restrict__ hb, const int* __restrict__ rowptr, const int* __restrict__ col,
    const u16* __restrict__ pB, const float* __restrict__ bl, u16* __restrict__ aggb)
{
  __shared__ u16 s_a[64][136];
  __shared__ u16 s_b[4*4*64*8];
  __shared__ float s_bias[64];
  const int t = threadIdx.x;
  const int n0 = blockIdx.x * 64;
  for (int idx = t; idx < 1024; idx += 256)
    ((short8*)s_b)[idx] = ((const short8*)pB)[idx];
  if (t < 64) s_bias[t] = bl[t];
  // hsb -> A cols [64,128): 64 rows x 4 short8
  {
    int r = t>>2, cg = t&3, node = n0 + r;
    short8* d8 = (short8*)&s_a[r][64 + cg*16];
    if (node < NN){
      const short8* sp = (const short8*)&hb[(size_t)node*HH + cg*16];
      d8[0] = sp[0]; d8[1] = sp[1];
    } else {
      u16* dz = (u16*)d8;
      #pragma unroll
      for (int q = 0; q < 16; ++q) dz[q] = 0;
    }
  }
  // gather: wave wv -> rows wv*16..+15
  const int wv = t >> 6, lane = t & 63;
  const int slot = lane >> 3;
  const int c8 = (lane & 7) * 8;
  for (int k = 0; k < 16; ++k){
    const int r = wv*16 + k;
    const int node = n0 + r;
    float a0=0.f,a1=0.f,a2=0.f,a3=0.f,a4=0.f,a5=0.f,a6=0.f,a7=0.f;
    int deg = 0;
    if (node < NN){
      int beg = rowptr[node], end = rowptr[node+1];
      deg = end - beg;
      for (int i = beg + slot; i < end; i += 8){
        int nb = col[i];
        short8 v = *(const short8*)&hb[(size_t)nb*HH + c8];
        a0 += bf2f((u16)v[0]); a1 += bf2f((u16)v[1]);
        a2 += bf2f((u16)v[2]); a3 += bf2f((u16)v[3]);
        a4 += bf2f((u16)v[4]); a5 += bf2f((u16)v[5]);
        a6 += bf2f((u16)v[6]); a7 += bf2f((u16)v[7]);
      }
    }
    #pragma unroll
    for (int m = 8; m <= 32; m <<= 1){
      a0 += __shfl_xor(a0, m); a1 += __shfl_xor(a1, m);
      a2 += __shfl_xor(a2, m); a3 += __shfl_xor(a3, m);
      a4 += __shfl_xor(a4, m); a5 += __shfl_xor(a5, m);
      a6 += __shfl_xor(a6, m); a7 += __shfl_xor(a7, m);
    }
    if (slot == 0){
      float invd = 1.f / fmaxf((float)deg, 1.f);
      u16* d = &s_a[r][c8];
      d[0]=f2bf(a0*invd); d[1]=f2bf(a1*invd); d[2]=f2bf(a2*invd); d[3]=f2bf(a3*invd);
      d[4]=f2bf(a4*invd); d[5]=f2bf(a5*invd); d[6]=f2bf(a6*invd); d[7]=f2bf(a7*invd);
    }
  }
  __syncthreads();
  const int nt = t >> 6;
  const int colp = lane & 15, rowg = lane >> 4;
  f32x4 acc[4];
  #pragma unroll
  for (int i = 0; i < 4; ++i) acc[i] = (f32x4){0.f,0.f,0.f,0.f};
  #pragma unroll
  for (int kt = 0; kt < 4; ++kt){
    short8 a = *(const short8*)&s_a[nt*16 + colp][kt*32 + rowg*8];
    #pragma unroll
    for (int ct = 0; ct < 4; ++ct){
      short8 b = *(const short8*)&s_b[((ct*4 + kt)*64 + lane)*8];
      acc[ct] = __builtin_amdgcn_mfma_f32_16x16x32_bf16(a, b, acc[ct], 0, 0, 0);
    }
  }
  #pragma unroll
  for (int reg = 0; reg < 4; ++reg){
    int node = n0 + nt*16 + rowg*4 + reg;
    if (node >= NN) continue;
    #pragma unroll
    for (int ct = 0; ct < 4; ++ct){
      int j = ct*16 + colp;
      float v = fmaxf(acc[ct][reg] + s_bias[j], 0.f);
      aggb[(size_t)node*HH + j] = f2bf(v);
    }
  }
}

// ---------------- both GRUs in one dispatch (blocks [0,NT): hs, [NT,2NT): hr) ----------------
__global__ __launch_bounds__(256) void k_gru2(
    float* __restrict__ hs, float* __restrict__ hr, const u16* __restrict__ amb,
    const float* __restrict__ gsW, const float* __restrict__ gsb,
    const float* __restrict__ grW, const float* __restrict__ grb,
    const u16* __restrict__ pBS, const u16* __restrict__ pBR,
    const float* __restrict__ sbih, const float* __restrict__ sbhh,
    const float* __restrict__ rbih, const float* __restrict__ rbhh,
    float* __restrict__ out_gate, u16* __restrict__ hsb, u16* __restrict__ hrb)
{
  __shared__ u16 s_b[2*12*2*64*8];      // 49152 B
  __shared__ u16 s_x[64][72];
  __shared__ u16 s_h[64][72];
  __shared__ float s_bi[192], s_bh[192];
  const int t = threadIdx.x;
  const bool isR = blockIdx.x >= NT;
  const int n0 = (isR ? (blockIdx.x - NT) : blockIdx.x) * 64;
  float* __restrict__ h = isR ? hr : hs;
  const u16* __restrict__ pB = isR ? pBR : pBS;
  const float* __restrict__ gW = isR ? grW : gsW;
  const float* __restrict__ gb = isR ? grb : gsb;
  const float* __restrict__ bih = isR ? rbih : sbih;
  const float* __restrict__ bhh = isR ? rbhh : sbhh;
  u16* __restrict__ bfout = isR ? hrb : hsb;
  for (int idx = t; idx < 3072; idx += 256)
    ((short8*)s_b)[idx] = ((const short8*)pB)[idx];
  if (t < 192){ s_bi[t] = bih[t]; s_bh[t] = bhh[t]; }
  const float gb0 = gb[0];
  {
    int r = t>>2, cg = t&3, node = n0 + r;
    u16* dh = &s_h[r][cg*16];
    u16* dx = &s_x[r][cg*16];
    if (node < NN){
      float hv[16];
      const float4* hp = (const float4*)&h[(size_t)node*HH + cg*16];
      #pragma unroll
      for (int q = 0; q < 4; ++q){
        float4 v = hp[q];
        hv[q*4+0]=v.x; hv[q*4+1]=v.y; hv[q*4+2]=v.z; hv[q*4+3]=v.w;
      }
      const float* gwp = &gW[cg*16];
      float p = 0.f;
      #pragma unroll
      for (int q = 0; q < 16; ++q) p += hv[q]*gwp[q];
      p += __shfl_xor(p, 1);
      p += __shfl_xor(p, 2);
      float gate = sigmoidf_(p + gb0);
      if (isR && cg == 0) out_gate[node] = gate;
      #pragma unroll
      for (int q = 0; q < 16; ++q) dh[q] = f2bf(hv[q]);
      const short8* ap = (const short8*)&amb[(size_t)node*HH + cg*16];
      short8 a0 = ap[0], a1 = ap[1];
      #pragma unroll
      for (int q = 0; q < 8; ++q){
        dx[q]   = f2bf(gate * bf2f((u16)a0[q]));
        dx[8+q] = f2bf(gate * bf2f((u16)a1[q]));
      }
    } else {
      #pragma unroll
      for (int q = 0; q < 16; ++q){ dh[q] = 0; dx[q] = 0; }
    }
  }
  __syncthreads();
  const int lane = t & 63, nt = t >> 6;
  const int colp = lane & 15, rowg = lane >> 4;
  f32x4 acc[24];
  #pragma unroll
  for (int i = 0; i < 24; ++i) acc[i] = (f32x4){0.f,0.f,0.f,0.f};
  const int arow = nt*16 + colp;
  #pragma unroll
  for (int kt = 0; kt < 2; ++kt){
    short8 ax = *(const short8*)&s_x[arow][kt*32 + rowg*8];
    short8 ah = *(const short8*)&s_h[arow][kt*32 + rowg*8];
    #pragma unroll
    for (int ct = 0; ct < 12; ++ct){
      short8 b0 = *(const short8*)&s_b[((ct*2 + kt)*64 + lane)*8];
      acc[ct] = __builtin_amdgcn_mfma_f32_16x16x32_bf16(ax, b0, acc[ct], 0, 0, 0);
      short8 b1 = *(const short8*)&s_b[(((12 + ct)*2 + kt)*64 + lane)*8];
      acc[12+ct] = __builtin_amdgcn_mfma_f32_16x16x32_bf16(ah, b1, acc[12+ct], 0, 0, 0);
    }
  }
  #pragma unroll
  for (int reg = 0; reg < 4; ++reg){
    int node = n0 + nt*16 + rowg*4 + reg;
    if (node >= NN) continue;
    #pragma unroll
    for (int jt = 0; jt < 4; ++jt){
      int j = jt*16 + colp;
      float ir = acc[jt][reg]      + s_bi[j];
      float iz = acc[4+jt][reg]    + s_bi[64+j];
      float in_ = acc[8+jt][reg]   + s_bi[128+j];
      float hr_ = acc[12+jt][reg]  + s_bh[j];
      float hz = acc[16+jt][reg]   + s_bh[64+j];
      float hn = acc[20+jt][reg]   + s_bh[128+j];
      float rg = sigmoidf_(ir + hr_);
      float zg = sigmoidf_(iz + hz);
      float ng = tanhf(in_ + rg*hn);
      size_t o = (size_t)node*HH + j;
      float ho = h[o];
      float hv = (1.f - zg)*ng + zg*ho;
      h[o] = hv;
      bfout[o] = f2bf(hv);
    }
  }
}

// ---------------- LSTM pre-activation GEMM via MFMA ----------------
__global__ __launch_bounds__(256) void k_lstmg(
    const float* __restrict__ q_star, const float* __restrict__ hin,
    const u16* __restrict__ pBl, const float* __restrict__ bih, const float* __restrict__ bhh,
    float* __restrict__ gbuf)
{
  __shared__ u16 s_a[64][72];
  __shared__ u16 s_b[6*2*64*8];
  const int t = threadIdx.x;
  const int mt = blockIdx.x >> 3, ntile = blockIdx.x & 7;
  const int g0 = mt * 64, c0 = ntile * 96;
  const int lane = t & 63, nt = t >> 6;
  const int colp = lane & 15, rowg = lane >> 4;
  f32x4 acc[6];
  #pragma unroll
  for (int ct = 0; ct < 6; ++ct){
    int j = c0 + ct*16 + colp;
    float bb = bih[j] + bhh[j];
    acc[ct] = (f32x4){bb, bb, bb, bb};
  }
  const int r = t>>2, cg = t&3;
  for (int kc = 0; kc < 9; ++kc){
    {
      const float* srcp = (kc < 6) ? &q_star[(size_t)(g0+r)*384 + kc*64 + cg*16]
                                   : &hin[(size_t)(g0+r)*192 + (kc-6)*64 + cg*16];
      u16* d = &s_a[r][cg*16];
      const float4* xp = (const float4*)srcp;
      #pragma unroll
      for (int q = 0; q < 4; ++q){
        float4 v = xp[q];
        d[q*4+0]=f2bf(v.x); d[q*4+1]=f2bf(v.y); d[q*4+2]=f2bf(v.z); d[q*4+3]=f2bf(v.w);
      }
    }
    for (int idx2 = t; idx2 < 768; idx2 += 256){
      int ctl = idx2 >> 7, rem = idx2 & 127;
      int ktl = rem >> 6, lane2 = rem & 63;
      int fsrc = ((ntile*6 + ctl)*18 + (kc*2 + ktl))*64 + lane2;
      ((short8*)s_b)[(ctl*2 + ktl)*64 + lane2] = ((const short8*)pBl)[fsrc];
    }
    __syncthreads();
    const int arow = nt*16 + colp;
    #pragma unroll
    for (int ktl = 0; ktl < 2; ++ktl){
      short8 a = *(const short8*)&s_a[arow][ktl*32 + rowg*8];
      #pragma unroll
      for (int ct = 0; ct < 6; ++ct){
        short8 b = *(const short8*)&s_b[((ct*2 + ktl)*64 + lane)*8];
        acc[ct] = __builtin_amdgcn_mfma_f32_16x16x32_bf16(a, b, acc[ct], 0, 0, 0);
      }
    }
    __syncthreads();
  }
  #pragma unroll
  for (int reg = 0; reg < 4; ++reg){
    int g = g0 + nt*16 + rowg*4 + reg;
    #pragma unroll
    for (int ct = 0; ct < 6; ++ct){
      int j = c0 + ct*16 + colp;
      gbuf[(size_t)g*768 + j] = acc[ct][reg];
    }
  }
}

// ---------------- fused LSTM epilogue + e-dot + segment softmax + weighted sum ----------------
__global__ __launch_bounds__(256) void k_attn2(
    const float* __restrict__ gbuf, const float* __restrict__ cin,
    float* __restrict__ hout, float* __restrict__ cout,
    const u16* __restrict__ projb, const u16* __restrict__ hsb, const u16* __restrict__ hrb,
    const int* __restrict__ growptr, float* __restrict__ q_star)
{
  __shared__ float s_q[192];
  __shared__ float s_e[512];
  __shared__ float red[256];
  const int b = blockIdx.x;
  const int beg = growptr[b], end = growptr[b+1];
  const int cnt = end - beg;
  const int t = threadIdx.x, wv = t>>6, lane = t&63;
  // LSTM pointwise epilogue for this graph
  if (t < 192){
    const float* gp = &gbuf[(size_t)b*768];
    float i_ = gp[t], f_ = gp[192+t], gg = gp[384+t], o_ = gp[576+t];
    float c = sigmoidf_(f_)*cin[(size_t)b*192 + t] + sigmoidf_(i_)*tanhf(gg);
    float hn = sigmoidf_(o_)*tanhf(c);
    cout[(size_t)b*192 + t] = c;
    hout[(size_t)b*192 + t] = hn;
    s_q[t] = hn;
  }
  __syncthreads();
  const float q0 = s_q[lane], q1 = s_q[64+lane], q2 = s_q[128+lane];
  const u16* fbase = (t < 64) ? projb : (t < 128) ? hsb : hrb;
  const int fcol = lane;
  float m_run = -3.0e38f, d_run = 0.f, racc = 0.f;
  for (int c0 = 0; c0 < cnt; c0 += 512){
    int cc = min(512, cnt - c0);
    for (int i = wv; i < cc; i += 4){
      size_t o = (size_t)(beg + c0 + i)*HH;
      float v = bf2f(projb[o+lane])*q0 + bf2f(hsb[o+lane])*q1 + bf2f(hrb[o+lane])*q2;
      #pragma unroll
      for (int off = 32; off > 0; off >>= 1) v += __shfl_down(v, off);
      if (lane == 0) s_e[i] = v;
    }
    __syncthreads();
    float mx = -3.0e38f;
    for (int i = t; i < cc; i += 256) mx = fmaxf(mx, s_e[i]);
    red[t] = mx; __syncthreads();
    for (int s = 128; s > 0; s >>= 1){ if (t < s) red[t] = fmaxf(red[t], red[t+s]); __syncthreads(); }
    float nm = fmaxf(m_run, red[0]);
    __syncthreads();
    float ps = 0.f;
    for (int i = t; i < cc; i += 256){ float ex = expf(s_e[i] - nm); s_e[i] = ex; ps += ex; }
    red[t] = ps; __syncthreads();
    for (int s = 128; s > 0; s >>= 1){ if (t < s) red[t] += red[t+s]; __syncthreads(); }
    float scale = (m_run > -1.0e38f) ? expf(m_run - nm) : 0.f;
    d_run = d_run*scale + red[0];
    racc *= scale;
    if (t < 192){
      for (int i = 0; i < cc; ++i)
        racc += s_e[i] * bf2f(fbase[(size_t)(beg + c0 + i)*HH + fcol]);
    }
    m_run = nm;
    __syncthreads();
  }
  if (t < 192){
    q_star[(size_t)b*384 + t] = s_q[t];
    q_star[(size_t)b*384 + 192 + t] = (cnt > 0) ? racc/d_run : 0.f;
  }
}

// ---------------- final GEMM via MFMA: out = PReLU(q_star@W_sp^T + b_sp) ----------------
__global__ __launch_bounds__(256) void k_fing(
    const float* __restrict__ q_star, const u16* __restrict__ pBf,
    const float* __restrict__ bias, const float* __restrict__ prelu_a,
    float* __restrict__ out)
{
  __shared__ u16 s_a[64][72];
  __shared__ u16 s_b[8*2*64*8];
  const int t = threadIdx.x;
  const int mt = blockIdx.x >> 3, ntile = blockIdx.x & 7;
  const int g0 = mt * 64, c0 = ntile * 128;
  const int lane = t & 63, nt = t >> 6;
  const int colp = lane & 15, rowg = lane >> 4;
  f32x4 acc[8];
  #pragma unroll
  for (int ct = 0; ct < 8; ++ct){
    float bb = bias[c0 + ct*16 + colp];
    acc[ct] = (f32x4){bb, bb, bb, bb};
  }
  const int r = t>>2, cg = t&3;
  for (int kc = 0; kc < 6; ++kc){
    {
      const float* srcp = &q_star[(size_t)(g0+r)*384 + kc*64 + cg*16];
      u16* d = &s_a[r][cg*16];
      const float4* xp = (const float4*)srcp;
      #pragma unroll
      for (int q = 0; q < 4; ++q){
        float4 v = xp[q];
        d[q*4+0]=f2bf(v.x); d[q*4+1]=f2bf(v.y); d[q*4+2]=f2bf(v.z); d[q*4+3]=f2bf(v.w);
      }
    }
    for (int idx2 = t; idx2 < 1024; idx2 += 256){
      int ctl = idx2 >> 7, rem = idx2 & 127;
      int ktl = rem >> 6, lane2 = rem & 63;
      int fsrc = (ntile*8 + ctl)*768 + (kc*2 + ktl)*64 + lane2;
      ((short8*)s_b)[(ctl*2 + ktl)*64 + lane2] = ((const short8*)pBf)[fsrc];
    }
    __syncthreads();
    const int arow = nt*16 + colp;
    #pragma unroll
    for (int ktl = 0; ktl < 2; ++ktl){
      short8 a = *(const short8*)&s_a[arow][ktl*32 + rowg*8];
      #pragma unroll
      for (int ct = 0; ct < 8; ++ct){
        short8 b = *(const short8*)&s_b[((ct*2 + ktl)*64 + lane)*8];
        acc[ct] = __builtin_amdgcn_mfma_f32_16x16x32_bf16(a, b, acc[ct], 0, 0, 0);
      }
    }
    __syncthreads();
  }
  const float a = prelu_a[0];
  #pragma unroll
  for (int reg = 0; reg < 4; ++reg){
    int g = g0 + nt*16 + rowg*4 + reg;
    #pragma unroll
    for (int ct = 0; ct < 8; ++ct){
      int j = c0 + ct*16 + colp;
      float z = acc[ct][reg];
      out[(size_t)g*RO + j] = (z >= 0.f) ? z : a*z;
    }
  }
}

extern "C" void kernel_launch(void* const* d_in, const int* in_sizes, int n_in,
                              void* d_out, int out_size, void* d_ws, size_t ws_size,
                              hipStream_t stream) {
  const float* x       = (const float*)d_in[0];
  const int*   ei      = (const int*)d_in[1];
  const int*   batch   = (const int*)d_in[3];
  const float* W_p     = (const float*)d_in[4];
  const float* b_p     = (const float*)d_in[5];
  const float* W_l     = (const float*)d_in[6];
  const float* b_l     = (const float*)d_in[7];
  const float* W_r     = (const float*)d_in[8];
  const float* gs_W    = (const float*)d_in[9];
  const float* gs_b    = (const float*)d_in[10];
  const float* gr_W    = (const float*)d_in[11];
  const float* gr_b    = (const float*)d_in[12];
  const float* grus_Wih= (const float*)d_in[13];
  const float* grus_Whh= (const float*)d_in[14];
  const float* grus_bih= (const float*)d_in[15];
  const float* grus_bhh= (const float*)d_in[16];
  const float* grur_Wih= (const float*)d_in[17];
  const float* grur_Whh= (const float*)d_in[18];
  const float* grur_bih= (const float*)d_in[19];
  const float* grur_bhh= (const float*)d_in[20];
  const float* lstm_Wih= (const float*)d_in[21];
  const float* lstm_Whh= (const float*)d_in[22];
  const float* lstm_bih= (const float*)d_in[23];
  const float* lstm_bhh= (const float*)d_in[24];
  const float* W_sp    = (const float*)d_in[25];
  const float* b_sp    = (const float*)d_in[26];
  const float* prelu_a = (const float*)d_in[27];

  float* out = (float*)d_out;
  char* w = (char*)d_ws;
  size_t off = 0;
  auto A = [&](size_t bytes){ size_t o = off; off += (bytes + 255) & ~(size_t)255; return o; };

  int*   bkcnt   = (int*)(w + A((size_t)NBK*4));
  int*   bkbase  = (int*)(w + A((size_t)(NBK+1)*4));
  int*   bcur    = (int*)(w + A((size_t)NBK*4));
  int*   rowptr  = (int*)(w + A((size_t)(NN+1)*4));
  int*   col     = (int*)(w + A((size_t)NE*4));
  int*   binned  = (int*)(w + A((size_t)NE*4));
  int*   gcnt    = (int*)(w + A((size_t)NB*4));
  int*   growptr = (int*)(w + A((size_t)(NB+1)*4));
  float* hs      = (float*)(w + A((size_t)NN*HH*4));
  float* hr      = (float*)(w + A((size_t)NN*HH*4));
  u16*   projb   = (u16*)(w + A((size_t)NN*HH*2));
  u16*   hsb     = (u16*)(w + A((size_t)NN*HH*2));
  u16*   hrb     = (u16*)(w + A((size_t)NN*HH*2));
  u16*   aggb    = (u16*)(w + A((size_t)NN*HH*2));   // am buffer
  float* qstar   = (float*)(w + A((size_t)NB*384*4));
  float* hlA     = (float*)(w + A((size_t)NB*192*4));
  float* clA     = (float*)(w + A((size_t)NB*192*4));
  float* hlB     = (float*)(w + A((size_t)NB*192*4));
  float* clB     = (float*)(w + A((size_t)NB*192*4));
  float* gbuf    = (float*)(w + A((size_t)NB*768*4));
  u16*   pB_proj = (u16*)(w + A((size_t)8192*2));
  u16*   pB_sage = (u16*)(w + A((size_t)8192*2));
  u16*   pB_gruS = (u16*)(w + A((size_t)24576*2));
  u16*   pB_gruR = (u16*)(w + A((size_t)24576*2));
  u16*   pB_lstm = (u16*)(w + A((size_t)55296*8*2));
  u16*   pB_fin  = (u16*)(w + A((size_t)49152*8*2));

  const int* src = ei;
  const int* dst = ei + NE;

  hipMemsetAsync(bkcnt, 0, (size_t)NBK*4, stream);
  hipMemsetAsync(gcnt,  0, (size_t)NB*4, stream);
  hipMemsetAsync(qstar, 0, (size_t)NB*384*4, stream);
  hipMemsetAsync(hlA,   0, (size_t)NB*192*4, stream);
  hipMemsetAsync(clA,   0, (size_t)NB*192*4, stream);

  k_bkcnt_prep<<<BINB + GCB + PREPB, 256, 0, stream>>>(dst, batch, bkcnt, gcnt,
                                                       W_p, W_l, W_r, grus_Wih, grus_Whh,
                                                       grur_Wih, grur_Whh, lstm_Wih, lstm_Whh, W_sp,
                                                       pB_proj, pB_sage, pB_gruS, pB_gruR,
                                                       pB_lstm, pB_fin);
  k_scan_small<<<2, 256, 0, stream>>>(bkcnt, bkbase, bcur, gcnt, growptr);
  k_bin  <<<BINB, 256, 0, stream>>>(src, dst, bcur, binned);
  k_place<<<NBK, 256, 0, stream>>>(binned, bkbase, rowptr, col);
  k_proj <<<NT, 256, 0, stream>>>(x, pB_proj, b_p, hs, hr, projb, hsb, hrb);

  float* gates_out = out + (size_t)NB*RO;
  for (int s = 0; s < 3; ++s){
    k_aggsage<<<NT, 256, 0, stream>>>(hsb, rowptr, col, pB_sage, b_l, aggb);
    k_gru2<<<2*NT, 256, 0, stream>>>(hs, hr, aggb, gs_W, gs_b, gr_W, gr_b,
                                     pB_gruS, pB_gruR,
                                     grus_bih, grus_bhh, grur_bih, grur_bhh,
                                     gates_out + (size_t)s*NN, hsb, hrb);
  }

  float* hin = hlA; float* cin = clA; float* hout = hlB; float* cout_ = clB;
  for (int t = 0; t < 3; ++t){
    k_lstmg<<<256, 256, 0, stream>>>(qstar, hin, pB_lstm, lstm_bih, lstm_bhh, gbuf);
    k_attn2<<<NB, 256, 0, stream>>>(gbuf, cin, hout, cout_, projb, hsb, hrb, growptr, qstar);
    float* th = hin; hin = hout; hout = th;
    float* tc = cin; cin = cout_; cout_ = tc;
  }

  k_fing<<<256, 256, 0, stream>>>(qstar, pB_fin, b_sp, prelu_a, out);
}

// Round 15
// 682.884 us; speedup vs baseline: 1.2311x; 1.2311x over previous
//
#include <hip/hip_runtime.h>
#include <math.h>

#define NN 100000      // nodes
#define NE 3200000     // edges
#define NIN 128
#define HH 64
#define NB 2048        // graphs
#define RO 1024

#define NT    1563     // (NN+63)/64
#define NBK   391      // ceil(NN/256) dst-buckets of 256 nodes
#define BINB  782      // ceil(NE/4096)
#define GCB   391      // ceil(NN/256) gcnt blocks
#define PCAP  10240    // k_place LDS staging capacity (edges)
#define PREPN 112640   // 8192 small + 55296 lstm + 49152 final frag ids
#define PREPB 440      // ceil(PREPN/256)
#define SRCMASK 0x1FFFF

typedef unsigned short u16;
typedef __attribute__((ext_vector_type(8))) short short8;
typedef __attribute__((ext_vector_type(4))) float f32x4;

__device__ __forceinline__ float sigmoidf_(float x){ return 1.f/(1.f+expf(-x)); }
__device__ __forceinline__ u16 f2bf(float f){
  unsigned u = __float_as_uint(f);
  return (u16)((u + 0x7FFFu + ((u>>16)&1u)) >> 16);
}
__device__ __forceinline__ float bf2f(u16 v){
  return __uint_as_float(((unsigned)v) << 16);
}

// ---------------- fused: bucket hist (LDS) + graph counting + weight prep ----------------
__global__ void k_bkcnt_prep(const int* __restrict__ dst, const int* __restrict__ batch,
                             int* __restrict__ bkcnt, int* __restrict__ gcnt,
                             const float* __restrict__ Wp, const float* __restrict__ Wl,
                             const float* __restrict__ Wr,
                             const float* __restrict__ sWih, const float* __restrict__ sWhh,
                             const float* __restrict__ rWih, const float* __restrict__ rWhh,
                             const float* __restrict__ lWih, const float* __restrict__ lWhh,
                             const float* __restrict__ Wsp,
                             u16* __restrict__ pB_proj, u16* __restrict__ pB_sage,
                             u16* __restrict__ pB_gruS, u16* __restrict__ pB_gruR,
                             u16* __restrict__ pB_lstm, u16* __restrict__ pB_fin){
  __shared__ int hist[NBK];
  const int t = threadIdx.x;
  if (blockIdx.x < BINB){
    for (int i = t; i < NBK; i += 256) hist[i] = 0;
    __syncthreads();
    const int e0 = blockIdx.x * 4096;
    const int cntE = min(4096, NE - e0);
    for (int idx = t; idx < cntE; idx += 256)
      atomicAdd(&hist[dst[e0 + idx] >> 8], 1);
    __syncthreads();
    for (int i = t; i < NBK; i += 256)
      if (hist[i]) atomicAdd(&bkcnt[i], hist[i]);
    return;
  }
  int r = blockIdx.x - BINB;
  if (r < GCB){
    int n = r*256 + t;
    if (n < NN) atomicAdd(&gcnt[batch[n]], 1);
    return;
  }
  int id = (r - GCB)*256 + t;
  if (id >= PREPN) return;
  const float* sp; u16* d;
  if (id < 1024){
    int fi = id; d = pB_proj + (size_t)fi*8;
    int lane = fi&63, kt=(fi>>6)&3, ct=fi>>8;
    int rr = ct*16 + (lane&15), k0 = kt*32 + (lane>>4)*8;
    sp = &Wp[(size_t)rr*NIN + k0];
  } else if (id < 2048){
    int fi = id - 1024; d = pB_sage + (size_t)fi*8;
    int lane = fi&63, kt=(fi>>6)&3, ct=fi>>8;
    int rr = ct*16 + (lane&15), k0 = kt*32 + (lane>>4)*8;
    sp = (k0 < 64) ? &Wl[(size_t)rr*HH + k0] : &Wr[(size_t)rr*HH + (k0-64)];
  } else if (id < 8192){
    int base = id - 2048;
    const float* Wih; const float* Whh; u16* pb; int fi;
    if (base < 3072){ pb = pB_gruS; Wih = sWih; Whh = sWhh; fi = base; }
    else            { pb = pB_gruR; Wih = rWih; Whh = rWhh; fi = base - 3072; }
    int lane = fi&63, kt=(fi>>6)&1, c2=fi>>7;
    const float* W2 = (c2 < 12) ? Wih : Whh;
    int ct = (c2 < 12) ? c2 : c2 - 12;
    int rr = ct*16 + (lane&15), k0 = kt*32 + (lane>>4)*8;
    sp = &W2[(size_t)rr*HH + k0];
    d = pb + (size_t)fi*8;
  } else if (id < 63488){
    // LSTM W = [Wih | Whh] as 768 x 576; frags (ctg 0..47, ktg 0..17, lane)
    int fi = id - 8192;
    int ctg = fi / 1152;
    int rem = fi - ctg*1152;
    int ktg = rem >> 6, lane = rem & 63;
    int rr = ctg*16 + (lane&15), k0 = ktg*32 + (lane>>4)*8;
    sp = (k0 < 384) ? &lWih[(size_t)rr*384 + k0] : &lWhh[(size_t)rr*192 + (k0-384)];
    d = pB_lstm + (size_t)fi*8;
  } else {
    // final W_sp 1024 x 384; frags (ctg 0..63, ktg 0..11, lane)
    int fi = id - 63488;
    int ctg = fi / 768;
    int rem = fi - ctg*768;
    int ktg = rem >> 6, lane = rem & 63;
    int rr = ctg*16 + (lane&15), k0 = ktg*32 + (lane>>4)*8;
    sp = &Wsp[(size_t)rr*384 + k0];
    d = pB_fin + (size_t)fi*8;
  }
  #pragma unroll
  for (int q = 0; q < 8; ++q) d[q] = f2bf(sp[q]);
}

// ---------------- small scans: block0 buckets(391), block1 graphs(2048) ----------------
__global__ __launch_bounds__(256) void k_scan_small(
    const int* __restrict__ bkcnt, int* __restrict__ bkbase, int* __restrict__ bcur,
    const int* __restrict__ gcnt, int* __restrict__ growptr){
  __shared__ int sb[256];
  const int t = threadIdx.x;
  if (blockIdx.x == 0){
    int loc[2]; int s = 0;
    #pragma unroll
    for (int q = 0; q < 2; ++q){ int i = t*2+q; loc[q] = (i < NBK) ? bkcnt[i] : 0; s += loc[q]; }
    sb[t] = s; __syncthreads();
    int v = s;
    for (int o = 1; o < 256; o <<= 1){
      int u = (t >= o) ? sb[t-o] : 0; __syncthreads();
      sb[t] += u; __syncthreads();
    }
    int run = sb[t] - v;
    #pragma unroll
    for (int q = 0; q < 2; ++q){
      int i = t*2+q;
      if (i < NBK){ bkbase[i] = run; bcur[i] = run; run += loc[q]; }
    }
    if (t == 255) bkbase[NBK] = run;    // = NE
  } else {
    int base = t*8;
    int loc[8]; int s = 0;
    #pragma unroll
    for (int q = 0; q < 8; ++q){ loc[q] = gcnt[base+q]; s += loc[q]; }
    sb[t] = s; __syncthreads();
    int v = s;
    for (int o = 1; o < 256; o <<= 1){
      int u = (t >= o) ? sb[t-o] : 0; __syncthreads();
      sb[t] += u; __syncthreads();
    }
    int run = sb[t] - v;
    #pragma unroll
    for (int q = 0; q < 8; ++q){ growptr[base+q] = run; run += loc[q]; }
    if (t == 255) growptr[NB] = run;
  }
}

// ---------------- pass 1: bin edges by dst>>8; packed payload src|(dlow<<17) ----------------
__global__ __launch_bounds__(256) void k_bin(
    const int* __restrict__ src, const int* __restrict__ dst,
    int* __restrict__ bcur, int* __restrict__ binned)
{
  __shared__ int hist[NBK];
  __shared__ int lbase[NBK];
  __shared__ int gbase[NBK];
  __shared__ int sb[512];
  __shared__ int stagep[4096];
  __shared__ u16 stageb[4096];
  const int t = threadIdx.x;
  const int e0 = blockIdx.x * 4096;
  const int cntE = min(4096, NE - e0);
  for (int i = t; i < NBK; i += 256) hist[i] = 0;
  __syncthreads();
  int2 ed[16];
  #pragma unroll
  for (int k = 0; k < 16; ++k){
    int idx = (k<<8) + t;
    if (idx < cntE){
      int e = e0 + idx;
      ed[k].x = src[e]; ed[k].y = dst[e];
      atomicAdd(&hist[ed[k].y >> 8], 1);
    } else ed[k].y = -1;
  }
  __syncthreads();
  sb[t]     = (t < NBK) ? hist[t] : 0;
  sb[t+256] = (t+256 < NBK) ? hist[t+256] : 0;
  __syncthreads();
  for (int off = 1; off < 512; off <<= 1){
    int v0 = (t >= off)     ? sb[t-off]     : 0;
    int v1 = (t+256 >= off) ? sb[t+256-off] : 0;
    __syncthreads();
    sb[t] += v0; sb[t+256] += v1;
    __syncthreads();
  }
  if (t < NBK)     lbase[t]     = sb[t]     - hist[t];
  if (t+256 < NBK) lbase[t+256] = sb[t+256] - hist[t+256];
  if (t < NBK)     gbase[t]     = (hist[t]     > 0) ? atomicAdd(&bcur[t],     hist[t])     : 0;
  if (t+256 < NBK) gbase[t+256] = (hist[t+256] > 0) ? atomicAdd(&bcur[t+256], hist[t+256]) : 0;
  __syncthreads();
  for (int i = t; i < NBK; i += 256) hist[i] = 0;
  __syncthreads();
  #pragma unroll
  for (int k = 0; k < 16; ++k){
    if (ed[k].y >= 0){
      int b = ed[k].y >> 8;
      int r = atomicAdd(&hist[b], 1);
      int p = lbase[b] + r;
      stagep[p] = ed[k].x | ((ed[k].y & 255) << 17);
      stageb[p] = (u16)b;
    }
  }
  __syncthreads();
  for (int i = t; i < cntE; i += 256){
    int b = stageb[i];
    binned[gbase[b] + (i - lbase[b])] = stagep[i];
  }
}

// ---------------- pass 2: per-bucket LDS counting sort; writes rowptr + col ----------------
__global__ __launch_bounds__(256) void k_place(
    const int* __restrict__ binned, const int* __restrict__ bkbase,
    int* __restrict__ rowptr, int* __restrict__ col)
{
  __shared__ int h[256];
  __shared__ int cur[256];
  __shared__ int sb2[256];
  __shared__ int stage[PCAP];
  const int t = threadIdx.x;
  const int b = blockIdx.x;
  const int n0 = b << 8;
  const int B0 = bkbase[b], B1 = bkbase[b+1];
  const int cntE = B1 - B0;
  h[t] = 0; __syncthreads();
  for (int i = t; i < cntE; i += 256){
    int e = binned[B0 + i];
    atomicAdd(&h[e >> 17], 1);
  }
  __syncthreads();
  sb2[t] = h[t]; __syncthreads();
  for (int off = 1; off < 256; off <<= 1){
    int v = (t >= off) ? sb2[t-off] : 0;
    __syncthreads();
    sb2[t] += v;
    __syncthreads();
  }
  int pre = sb2[t] - h[t];               // exclusive prefix within bucket
  if (n0 + t < NN) rowptr[n0 + t] = B0 + pre;
  if (b == NBK-1 && t == 0) rowptr[NN] = B1;   // = NE
  if (cntE <= PCAP){
    cur[t] = pre;
    __syncthreads();
    for (int i = t; i < cntE; i += 256){
      int e = binned[B0 + i];
      int idx = atomicAdd(&cur[e >> 17], 1);
      stage[idx] = e & SRCMASK;
    }
    __syncthreads();
    for (int i = t; i < cntE; i += 256) col[B0 + i] = stage[i];
  } else {
    cur[t] = B0 + pre;                    // global cursors (rare fallback)
    __syncthreads();
    for (int i = t; i < cntE; i += 256){
      int e = binned[B0 + i];
      int p = atomicAdd(&cur[e >> 17], 1);
      col[p] = e & SRCMASK;
    }
  }
}

// ---------------- proj = relu(x@W_p^T + b) via MFMA; init hs, hr, projb, hsb, hrb ----------------
__global__ __launch_bounds__(256) void k_proj(
    const float* __restrict__ x, const u16* __restrict__ pB, const float* __restrict__ bp,
    float* __restrict__ hs, float* __restrict__ hr,
    u16* __restrict__ projb, u16* __restrict__ hsb, u16* __restrict__ hrb)
{
  __shared__ u16 s_a[64][136];
  __shared__ u16 s_b[4*4*64*8];
  __shared__ float s_bias[64];
  const int t = threadIdx.x;
  const int n0 = blockIdx.x * 64;
  for (int idx = t; idx < 1024; idx += 256)
    ((short8*)s_b)[idx] = ((const short8*)pB)[idx];
  if (t < 64) s_bias[t] = bp[t];
  {
    int r = t>>2, cg = t&3, node = n0 + r;
    u16* d = &s_a[r][cg*32];
    if (node < NN){
      const float4* xp = (const float4*)&x[(size_t)node*NIN + cg*32];
      #pragma unroll
      for (int q = 0; q < 8; ++q){
        float4 v = xp[q];
        d[q*4+0]=f2bf(v.x); d[q*4+1]=f2bf(v.y); d[q*4+2]=f2bf(v.z); d[q*4+3]=f2bf(v.w);
      }
    } else {
      #pragma unroll
      for (int q = 0; q < 32; ++q) d[q] = 0;
    }
  }
  __syncthreads();
  const int lane = t & 63, nt = t >> 6;
  const int colp = lane & 15, rowg = lane >> 4;
  f32x4 acc[4];
  #pragma unroll
  for (int i = 0; i < 4; ++i) acc[i] = (f32x4){0.f,0.f,0.f,0.f};
  #pragma unroll
  for (int kt = 0; kt < 4; ++kt){
    short8 a = *(const short8*)&s_a[nt*16 + colp][kt*32 + rowg*8];
    #pragma unroll
    for (int ct = 0; ct < 4; ++ct){
      short8 b = *(const short8*)&s_b[((ct*4 + kt)*64 + lane)*8];
      acc[ct] = __builtin_amdgcn_mfma_f32_16x16x32_bf16(a, b, acc[ct], 0, 0, 0);
    }
  }
  #pragma unroll
  for (int reg = 0; reg < 4; ++reg){
    int node = n0 + nt*16 + rowg*4 + reg;
    if (node >= NN) continue;
    #pragma unroll
    for (int ct = 0; ct < 4; ++ct){
      int j = ct*16 + colp;
      float v = fmaxf(acc[ct][reg] + s_bias[j], 0.f);
      size_t o = (size_t)node*HH + j;
      hs[o] = v; hr[o] = v;
      u16 bv = f2bf(v);
      projb[o] = bv; hsb[o] = bv; hrb[o] = bv;
    }
  }
}

// ---------------- aggb[n] = mean over neighbors of hsb (bf16 in/out); 8-nbr ILP ----------------
__global__ __launch_bounds__(256) void k_agg(
    const u16* __restrict__ hb, const int* __restrict__ rowptr,
    const int* __restrict__ col, u16* __restrict__ aggb)
{
  int node = blockIdx.x*4 + (threadIdx.x >> 6);
  int lane = threadIdx.x & 63;
  if (node >= NN) return;
  int beg = rowptr[node], end = rowptr[node+1];
  const int slot = lane >> 3;
  const int c8 = (lane & 7) * 8;
  float a0=0.f,a1=0.f,a2=0.f,a3=0.f,a4=0.f,a5=0.f,a6=0.f,a7=0.f;
  for (int i = beg + slot; i < end; i += 8){
    int nb = col[i];
    short8 v = *(const short8*)&hb[(size_t)nb*HH + c8];
    a0 += bf2f((u16)v[0]); a1 += bf2f((u16)v[1]);
    a2 += bf2f((u16)v[2]); a3 += bf2f((u16)v[3]);
    a4 += bf2f((u16)v[4]); a5 += bf2f((u16)v[5]);
    a6 += bf2f((u16)v[6]); a7 += bf2f((u16)v[7]);
  }
  #pragma unroll
  for (int m = 8; m <= 32; m <<= 1){
    a0 += __shfl_xor(a0, m); a1 += __shfl_xor(a1, m);
    a2 += __shfl_xor(a2, m); a3 += __shfl_xor(a3, m);
    a4 += __shfl_xor(a4, m); a5 += __shfl_xor(a5, m);
    a6 += __shfl_xor(a6, m); a7 += __shfl_xor(a7, m);
  }
  if (slot == 0){
    float invd = 1.f / fmaxf((float)(end - beg), 1.f);
    short8 o;
    o[0]=(short)f2bf(a0*invd); o[1]=(short)f2bf(a1*invd);
    o[2]=(short)f2bf(a2*invd); o[3]=(short)f2bf(a3*invd);
    o[4]=(short)f2bf(a4*invd); o[5]=(short)f2bf(a5*invd);
    o[6]=(short)f2bf(a6*invd); o[7]=(short)f2bf(a7*invd);
    *(short8*)&aggb[(size_t)node*HH + c8] = o;
  }
}

// ---------------- am = relu([agg|hs]@[Wl;Wr]^T + bl) via MFMA, bf16 in-place ----------------
__global__ __launch_bounds__(256) void k_sage(
    const u16* __restrict__ hsb, const u16* __restrict__ pB,
    const float* __restrict__ bl, u16* __restrict__ aggb)
{
  __shared__ u16 s_a[64][136];
  __shared__ u16 s_b[4*4*64*8];
  __shared__ float s_bias[64];
  const int t = threadIdx.x;
  const int n0 = blockIdx.x * 64;
  for (int idx = t; idx < 1024; idx += 256)
    ((short8*)s_b)[idx] = ((const short8*)pB)[idx];
  if (t < 64) s_bias[t] = bl[t];
  {
    int r = t>>2, cg = t&3, node = n0 + r;
    short8* d8 = (short8*)&s_a[r][cg*32];
    if (node < NN){
      const short8* sp = (cg < 2) ? (const short8*)&aggb[(size_t)node*HH + cg*32]
                                  : (const short8*)&hsb[(size_t)node*HH + (cg-2)*32];
      d8[0] = sp[0]; d8[1] = sp[1]; d8[2] = sp[2]; d8[3] = sp[3];
    } else {
      u16* dz = (u16*)d8;
      #pragma unroll
      for (int q = 0; q < 32; ++q) dz[q] = 0;
    }
  }
  __syncthreads();
  const int lane = t & 63, nt = t >> 6;
  const int colp = lane & 15, rowg = lane >> 4;
  f32x4 acc[4];
  #pragma unroll
  for (int i = 0; i < 4; ++i) acc[i] = (f32x4){0.f,0.f,0.f,0.f};
  #pragma unroll
  for (int kt = 0; kt < 4; ++kt){
    short8 a = *(const short8*)&s_a[nt*16 + colp][kt*32 + rowg*8];
    #pragma unroll
    for (int ct = 0; ct < 4; ++ct){
      short8 b = *(const short8*)&s_b[((ct*4 + kt)*64 + lane)*8];
      acc[ct] = __builtin_amdgcn_mfma_f32_16x16x32_bf16(a, b, acc[ct], 0, 0, 0);
    }
  }
  __syncthreads();
  #pragma unroll
  for (int reg = 0; reg < 4; ++reg){
    int node = n0 + nt*16 + rowg*4 + reg;
    if (node >= NN) continue;
    #pragma unroll
    for (int ct = 0; ct < 4; ++ct){
      int j = ct*16 + colp;
      float v = fmaxf(acc[ct][reg] + s_bias[j], 0.f);
      aggb[(size_t)node*HH + j] = f2bf(v);
    }
  }
}

// ---------------- both GRUs in one dispatch (blocks [0,NT): hs, [NT,2NT): hr) ----------------
__global__ __launch_bounds__(256) void k_gru2(
    float* __restrict__ hs, float* __restrict__ hr, const u16* __restrict__ amb,
    const float* __restrict__ gsW, const float* __restrict__ gsb,
    const float* __restrict__ grW, const float* __restrict__ grb,
    const u16* __restrict__ pBS, const u16* __restrict__ pBR,
    const float* __restrict__ sbih, const float* __restrict__ sbhh,
    const float* __restrict__ rbih, const float* __restrict__ rbhh,
    float* __restrict__ out_gate, u16* __restrict__ hsb, u16* __restrict__ hrb)
{
  __shared__ u16 s_b[2*12*2*64*8];      // 49152 B
  __shared__ u16 s_x[64][72];
  __shared__ u16 s_h[64][72];
  __shared__ float s_bi[192], s_bh[192];
  const int t = threadIdx.x;
  const bool isR = blockIdx.x >= NT;
  const int n0 = (isR ? (blockIdx.x - NT) : blockIdx.x) * 64;
  float* __restrict__ h = isR ? hr : hs;
  const u16* __restrict__ pB = isR ? pBR : pBS;
  const float* __restrict__ gW = isR ? grW : gsW;
  const float* __restrict__ gb = isR ? grb : gsb;
  const float* __restrict__ bih = isR ? rbih : sbih;
  const float* __restrict__ bhh = isR ? rbhh : sbhh;
  u16* __restrict__ bfout = isR ? hrb : hsb;
  for (int idx = t; idx < 3072; idx += 256)
    ((short8*)s_b)[idx] = ((const short8*)pB)[idx];
  if (t < 192){ s_bi[t] = bih[t]; s_bh[t] = bhh[t]; }
  const float gb0 = gb[0];
  {
    int r = t>>2, cg = t&3, node = n0 + r;
    u16* dh = &s_h[r][cg*16];
    u16* dx = &s_x[r][cg*16];
    if (node < NN){
      float hv[16];
      const float4* hp = (const float4*)&h[(size_t)node*HH + cg*16];
      #pragma unroll
      for (int q = 0; q < 4; ++q){
        float4 v = hp[q];
        hv[q*4+0]=v.x; hv[q*4+1]=v.y; hv[q*4+2]=v.z; hv[q*4+3]=v.w;
      }
      const float* gwp = &gW[cg*16];
      float p = 0.f;
      #pragma unroll
      for (int q = 0; q < 16; ++q) p += hv[q]*gwp[q];
      p += __shfl_xor(p, 1);
      p += __shfl_xor(p, 2);
      float gate = sigmoidf_(p + gb0);
      if (isR && cg == 0) out_gate[node] = gate;
      #pragma unroll
      for (int q = 0; q < 16; ++q) dh[q] = f2bf(hv[q]);
      const short8* ap = (const short8*)&amb[(size_t)node*HH + cg*16];
      short8 a0 = ap[0], a1 = ap[1];
      #pragma unroll
      for (int q = 0; q < 8; ++q){
        dx[q]   = f2bf(gate * bf2f((u16)a0[q]));
        dx[8+q] = f2bf(gate * bf2f((u16)a1[q]));
      }
    } else {
      #pragma unroll
      for (int q = 0; q < 16; ++q){ dh[q] = 0; dx[q] = 0; }
    }
  }
  __syncthreads();
  const int lane = t & 63, nt = t >> 6;
  const int colp = lane & 15, rowg = lane >> 4;
  f32x4 acc[24];
  #pragma unroll
  for (int i = 0; i < 24; ++i) acc[i] = (f32x4){0.f,0.f,0.f,0.f};
  const int arow = nt*16 + colp;
  #pragma unroll
  for (int kt = 0; kt < 2; ++kt){
    short8 ax = *(const short8*)&s_x[arow][kt*32 + rowg*8];
    short8 ah = *(const short8*)&s_h[arow][kt*32 + rowg*8];
    #pragma unroll
    for (int ct = 0; ct < 12; ++ct){
      short8 b0 = *(const short8*)&s_b[((ct*2 + kt)*64 + lane)*8];
      acc[ct] = __builtin_amdgcn_mfma_f32_16x16x32_bf16(ax, b0, acc[ct], 0, 0, 0);
      short8 b1 = *(const short8*)&s_b[(((12 + ct)*2 + kt)*64 + lane)*8];
      acc[12+ct] = __builtin_amdgcn_mfma_f32_16x16x32_bf16(ah, b1, acc[12+ct], 0, 0, 0);
    }
  }
  #pragma unroll
  for (int reg = 0; reg < 4; ++reg){
    int node = n0 + nt*16 + rowg*4 + reg;
    if (node >= NN) continue;
    #pragma unroll
    for (int jt = 0; jt < 4; ++jt){
      int j = jt*16 + colp;
      float ir = acc[jt][reg]      + s_bi[j];
      float iz = acc[4+jt][reg]    + s_bi[64+j];
      float in_ = acc[8+jt][reg]   + s_bi[128+j];
      float hr_ = acc[12+jt][reg]  + s_bh[j];
      float hz = acc[16+jt][reg]   + s_bh[64+j];
      float hn = acc[20+jt][reg]   + s_bh[128+j];
      float rg = sigmoidf_(ir + hr_);
      float zg = sigmoidf_(iz + hz);
      float ng = tanhf(in_ + rg*hn);
      size_t o = (size_t)node*HH + j;
      float ho = h[o];
      float hv = (1.f - zg)*ng + zg*ho;
      h[o] = hv;
      bfout[o] = f2bf(hv);
    }
  }
}

// ---------------- LSTM pre-activation GEMM via MFMA ----------------
__global__ __launch_bounds__(256) void k_lstmg(
    const float* __restrict__ q_star, const float* __restrict__ hin,
    const u16* __restrict__ pBl, const float* __restrict__ bih, const float* __restrict__ bhh,
    float* __restrict__ gbuf)
{
  __shared__ u16 s_a[64][72];
  __shared__ u16 s_b[6*2*64*8];
  const int t = threadIdx.x;
  const int mt = blockIdx.x >> 3, ntile = blockIdx.x & 7;
  const int g0 = mt * 64, c0 = ntile * 96;
  const int lane = t & 63, nt = t >> 6;
  const int colp = lane & 15, rowg = lane >> 4;
  f32x4 acc[6];
  #pragma unroll
  for (int ct = 0; ct < 6; ++ct){
    int j = c0 + ct*16 + colp;
    float bb = bih[j] + bhh[j];
    acc[ct] = (f32x4){bb, bb, bb, bb};
  }
  const int r = t>>2, cg = t&3;
  for (int kc = 0; kc < 9; ++kc){
    {
      const float* srcp = (kc < 6) ? &q_star[(size_t)(g0+r)*384 + kc*64 + cg*16]
                                   : &hin[(size_t)(g0+r)*192 + (kc-6)*64 + cg*16];
      u16* d = &s_a[r][cg*16];
      const float4* xp = (const float4*)srcp;
      #pragma unroll
      for (int q = 0; q < 4; ++q){
        float4 v = xp[q];
        d[q*4+0]=f2bf(v.x); d[q*4+1]=f2bf(v.y); d[q*4+2]=f2bf(v.z); d[q*4+3]=f2bf(v.w);
      }
    }
    for (int idx2 = t; idx2 < 768; idx2 += 256){
      int ctl = idx2 >> 7, rem = idx2 & 127;
      int ktl = rem >> 6, lane2 = rem & 63;
      int fsrc = ((ntile*6 + ctl)*18 + (kc*2 + ktl))*64 + lane2;
      ((short8*)s_b)[(ctl*2 + ktl)*64 + lane2] = ((const short8*)pBl)[fsrc];
    }
    __syncthreads();
    const int arow = nt*16 + colp;
    #pragma unroll
    for (int ktl = 0; ktl < 2; ++ktl){
      short8 a = *(const short8*)&s_a[arow][ktl*32 + rowg*8];
      #pragma unroll
      for (int ct = 0; ct < 6; ++ct){
        short8 b = *(const short8*)&s_b[((ct*2 + ktl)*64 + lane)*8];
        acc[ct] = __builtin_amdgcn_mfma_f32_16x16x32_bf16(a, b, acc[ct], 0, 0, 0);
      }
    }
    __syncthreads();
  }
  #pragma unroll
  for (int reg = 0; reg < 4; ++reg){
    int g = g0 + nt*16 + rowg*4 + reg;
    #pragma unroll
    for (int ct = 0; ct < 6; ++ct){
      int j = c0 + ct*16 + colp;
      gbuf[(size_t)g*768 + j] = acc[ct][reg];
    }
  }
}

// ---------------- fused LSTM epilogue + e-dot + segment softmax + weighted sum ----------------
__global__ __launch_bounds__(256) void k_attn2(
    const float* __restrict__ gbuf, const float* __restrict__ cin,
    float* __restrict__ hout, float* __restrict__ cout,
    const u16* __restrict__ projb, const u16* __restrict__ hsb, const u16* __restrict__ hrb,
    const int* __restrict__ growptr, float* __restrict__ q_star)
{
  __shared__ float s_q[192];
  __shared__ float s_e[512];
  __shared__ float red[256];
  const int b = blockIdx.x;
  const int beg = growptr[b], end = growptr[b+1];
  const int cnt = end - beg;
  const int t = threadIdx.x, wv = t>>6, lane = t&63;
  // LSTM pointwise epilogue for this graph
  if (t < 192){
    const float* gp = &gbuf[(size_t)b*768];
    float i_ = gp[t], f_ = gp[192+t], gg = gp[384+t], o_ = gp[576+t];
    float c = sigmoidf_(f_)*cin[(size_t)b*192 + t] + sigmoidf_(i_)*tanhf(gg);
    float hn = sigmoidf_(o_)*tanhf(c);
    cout[(size_t)b*192 + t] = c;
    hout[(size_t)b*192 + t] = hn;
    s_q[t] = hn;
  }
  __syncthreads();
  const float q0 = s_q[lane], q1 = s_q[64+lane], q2 = s_q[128+lane];
  const u16* fbase = (t < 64) ? projb : (t < 128) ? hsb : hrb;
  const int fcol = lane;
  float m_run = -3.0e38f, d_run = 0.f, racc = 0.f;
  for (int c0 = 0; c0 < cnt; c0 += 512){
    int cc = min(512, cnt - c0);
    for (int i = wv; i < cc; i += 4){
      size_t o = (size_t)(beg + c0 + i)*HH;
      float v = bf2f(projb[o+lane])*q0 + bf2f(hsb[o+lane])*q1 + bf2f(hrb[o+lane])*q2;
      #pragma unroll
      for (int off = 32; off > 0; off >>= 1) v += __shfl_down(v, off);
      if (lane == 0) s_e[i] = v;
    }
    __syncthreads();
    float mx = -3.0e38f;
    for (int i = t; i < cc; i += 256) mx = fmaxf(mx, s_e[i]);
    red[t] = mx; __syncthreads();
    for (int s = 128; s > 0; s >>= 1){ if (t < s) red[t] = fmaxf(red[t], red[t+s]); __syncthreads(); }
    float nm = fmaxf(m_run, red[0]);
    __syncthreads();
    float ps = 0.f;
    for (int i = t; i < cc; i += 256){ float ex = expf(s_e[i] - nm); s_e[i] = ex; ps += ex; }
    red[t] = ps; __syncthreads();
    for (int s = 128; s > 0; s >>= 1){ if (t < s) red[t] += red[t+s]; __syncthreads(); }
    float scale = (m_run > -1.0e38f) ? expf(m_run - nm) : 0.f;
    d_run = d_run*scale + red[0];
    racc *= scale;
    if (t < 192){
      for (int i = 0; i < cc; ++i)
        racc += s_e[i] * bf2f(fbase[(size_t)(beg + c0 + i)*HH + fcol]);
    }
    m_run = nm;
    __syncthreads();
  }
  if (t < 192){
    q_star[(size_t)b*384 + t] = s_q[t];
    q_star[(size_t)b*384 + 192 + t] = (cnt > 0) ? racc/d_run : 0.f;
  }
}

// ---------------- final GEMM via MFMA: out = PReLU(q_star@W_sp^T + b_sp) ----------------
__global__ __launch_bounds__(256) void k_fing(
    const float* __restrict__ q_star, const u16* __restrict__ pBf,
    const float* __restrict__ bias, const float* __restrict__ prelu_a,
    float* __restrict__ out)
{
  __shared__ u16 s_a[64][72];
  __shared__ u16 s_b[8*2*64*8];
  const int t = threadIdx.x;
  const int mt = blockIdx.x >> 3, ntile = blockIdx.x & 7;
  const int g0 = mt * 64, c0 = ntile * 128;
  const int lane = t & 63, nt = t >> 6;
  const int colp = lane & 15, rowg = lane >> 4;
  f32x4 acc[8];
  #pragma unroll
  for (int ct = 0; ct < 8; ++ct){
    float bb = bias[c0 + ct*16 + colp];
    acc[ct] = (f32x4){bb, bb, bb, bb};
  }
  const int r = t>>2, cg = t&3;
  for (int kc = 0; kc < 6; ++kc){
    {
      const float* srcp = &q_star[(size_t)(g0+r)*384 + kc*64 + cg*16];
      u16* d = &s_a[r][cg*16];
      const float4* xp = (const float4*)srcp;
      #pragma unroll
      for (int q = 0; q < 4; ++q){
        float4 v = xp[q];
        d[q*4+0]=f2bf(v.x); d[q*4+1]=f2bf(v.y); d[q*4+2]=f2bf(v.z); d[q*4+3]=f2bf(v.w);
      }
    }
    for (int idx2 = t; idx2 < 1024; idx2 += 256){
      int ctl = idx2 >> 7, rem = idx2 & 127;
      int ktl = rem >> 6, lane2 = rem & 63;
      int fsrc = (ntile*8 + ctl)*768 + (kc*2 + ktl)*64 + lane2;
      ((short8*)s_b)[(ctl*2 + ktl)*64 + lane2] = ((const short8*)pBf)[fsrc];
    }
    __syncthreads();
    const int arow = nt*16 + colp;
    #pragma unroll
    for (int ktl = 0; ktl < 2; ++ktl){
      short8 a = *(const short8*)&s_a[arow][ktl*32 + rowg*8];
      #pragma unroll
      for (int ct = 0; ct < 8; ++ct){
        short8 b = *(const short8*)&s_b[((ct*2 + ktl)*64 + lane)*8];
        acc[ct] = __builtin_amdgcn_mfma_f32_16x16x32_bf16(a, b, acc[ct], 0, 0, 0);
      }
    }
    __syncthreads();
  }
  const float a = prelu_a[0];
  #pragma unroll
  for (int reg = 0; reg < 4; ++reg){
    int g = g0 + nt*16 + rowg*4 + reg;
    #pragma unroll
    for (int ct = 0; ct < 8; ++ct){
      int j = c0 + ct*16 + colp;
      float z = acc[ct][reg];
      out[(size_t)g*RO + j] = (z >= 0.f) ? z : a*z;
    }
  }
}

extern "C" void kernel_launch(void* const* d_in, const int* in_sizes, int n_in,
                              void* d_out, int out_size, void* d_ws, size_t ws_size,
                              hipStream_t stream) {
  const float* x       = (const float*)d_in[0];
  const int*   ei      = (const int*)d_in[1];
  const int*   batch   = (const int*)d_in[3];
  const float* W_p     = (const float*)d_in[4];
  const float* b_p     = (const float*)d_in[5];
  const float* W_l     = (const float*)d_in[6];
  const float* b_l     = (const float*)d_in[7];
  const float* W_r     = (const float*)d_in[8];
  const float* gs_W    = (const float*)d_in[9];
  const float* gs_b    = (const float*)d_in[10];
  const float* gr_W    = (const float*)d_in[11];
  const float* gr_b    = (const float*)d_in[12];
  const float* grus_Wih= (const float*)d_in[13];
  const float* grus_Whh= (const float*)d_in[14];
  const float* grus_bih= (const float*)d_in[15];
  const float* grus_bhh= (const float*)d_in[16];
  const float* grur_Wih= (const float*)d_in[17];
  const float* grur_Whh= (const float*)d_in[18];
  const float* grur_bih= (const float*)d_in[19];
  const float* grur_bhh= (const float*)d_in[20];
  const float* lstm_Wih= (const float*)d_in[21];
  const float* lstm_Whh= (const float*)d_in[22];
  const float* lstm_bih= (const float*)d_in[23];
  const float* lstm_bhh= (const float*)d_in[24];
  const float* W_sp    = (const float*)d_in[25];
  const float* b_sp    = (const float*)d_in[26];
  const float* prelu_a = (const float*)d_in[27];

  float* out = (float*)d_out;
  char* w = (char*)d_ws;
  size_t off = 0;
  auto A = [&](size_t bytes){ size_t o = off; off += (bytes + 255) & ~(size_t)255; return o; };

  int*   bkcnt   = (int*)(w + A((size_t)NBK*4));
  int*   bkbase  = (int*)(w + A((size_t)(NBK+1)*4));
  int*   bcur    = (int*)(w + A((size_t)NBK*4));
  int*   rowptr  = (int*)(w + A((size_t)(NN+1)*4));
  int*   col     = (int*)(w + A((size_t)NE*4));
  int*   binned  = (int*)(w + A((size_t)NE*4));
  int*   gcnt    = (int*)(w + A((size_t)NB*4));
  int*   growptr = (int*)(w + A((size_t)(NB+1)*4));
  float* hs      = (float*)(w + A((size_t)NN*HH*4));
  float* hr      = (float*)(w + A((size_t)NN*HH*4));
  u16*   projb   = (u16*)(w + A((size_t)NN*HH*2));
  u16*   hsb     = (u16*)(w + A((size_t)NN*HH*2));
  u16*   hrb     = (u16*)(w + A((size_t)NN*HH*2));
  u16*   aggb    = (u16*)(w + A((size_t)NN*HH*2));   // am buffer
  float* qstar   = (float*)(w + A((size_t)NB*384*4));
  float* hlA     = (float*)(w + A((size_t)NB*192*4));
  float* clA     = (float*)(w + A((size_t)NB*192*4));
  float* hlB     = (float*)(w + A((size_t)NB*192*4));
  float* clB     = (float*)(w + A((size_t)NB*192*4));
  float* gbuf    = (float*)(w + A((size_t)NB*768*4));
  u16*   pB_proj = (u16*)(w + A((size_t)8192*2));
  u16*   pB_sage = (u16*)(w + A((size_t)8192*2));
  u16*   pB_gruS = (u16*)(w + A((size_t)24576*2));
  u16*   pB_gruR = (u16*)(w + A((size_t)24576*2));
  u16*   pB_lstm = (u16*)(w + A((size_t)55296*8*2));
  u16*   pB_fin  = (u16*)(w + A((size_t)49152*8*2));

  const int* src = ei;
  const int* dst = ei + NE;

  hipMemsetAsync(bkcnt, 0, (size_t)NBK*4, stream);
  hipMemsetAsync(gcnt,  0, (size_t)NB*4, stream);
  hipMemsetAsync(qstar, 0, (size_t)NB*384*4, stream);
  hipMemsetAsync(hlA,   0, (size_t)NB*192*4, stream);
  hipMemsetAsync(clA,   0, (size_t)NB*192*4, stream);

  k_bkcnt_prep<<<BINB + GCB + PREPB, 256, 0, stream>>>(dst, batch, bkcnt, gcnt,
                                                       W_p, W_l, W_r, grus_Wih, grus_Whh,
                                                       grur_Wih, grur_Whh, lstm_Wih, lstm_Whh, W_sp,
                                                       pB_proj, pB_sage, pB_gruS, pB_gruR,
                                                       pB_lstm, pB_fin);
  k_scan_small<<<2, 256, 0, stream>>>(bkcnt, bkbase, bcur, gcnt, growptr);
  k_bin  <<<BINB, 256, 0, stream>>>(src, dst, bcur, binned);
  k_place<<<NBK, 256, 0, stream>>>(binned, bkbase, rowptr, col);
  k_proj <<<NT, 256, 0, stream>>>(x, pB_proj, b_p, hs, hr, projb, hsb, hrb);

  float* gates_out = out + (size_t)NB*RO;
  for (int s = 0; s < 3; ++s){
    k_agg <<<NN/4, 256, 0, stream>>>(hsb, rowptr, col, aggb);
    k_sage<<<NT, 256, 0, stream>>>(hsb, pB_sage, b_l, aggb);
    k_gru2<<<2*NT, 256, 0, stream>>>(hs, hr, aggb, gs_W, gs_b, gr_W, gr_b,
                                     pB_gruS, pB_gruR,
                                     grus_bih, grus_bhh, grur_bih, grur_bhh,
                                     gates_out + (size_t)s*NN, hsb, hrb);
  }

  float* hin = hlA; float* cin = clA; float* hout = hlB; float* cout_ = clB;
  for (int t = 0; t < 3; ++t){
    k_lstmg<<<256, 256, 0, stream>>>(qstar, hin, pB_lstm, lstm_bih, lstm_bhh, gbuf);
    k_attn2<<<NB, 256, 0, stream>>>(gbuf, cin, hout, cout_, projb, hsb, hrb, growptr, qstar);
    float* th = hin; hin = hout; hout = th;
    float* tc = cin; cin = cout_; cout_ = tc;
  }

  k_fing<<<256, 256, 0, stream>>>(qstar, pB_fin, b_sp, prelu_a, out);
}